// Round 12
// baseline (236.661 us; speedup 1.0000x reference)
//
#include <hip/hip_runtime.h>

#define LN_EPS 1e-5f

// ---------------------------------------------------------------------------
// ws layout (floats)
// ---------------------------------------------------------------------------
constexpr int T1_OFF   = 0;                       // 64*128*128 = 1048576
constexpr int WT2_OFF  = 1048576;                 // 25*4096: [k][tid] float4 over o-quads
constexpr int WT3_OFF  = WT2_OFF + 102400;        // 25*4096
constexpr int WT4_OFF  = WT3_OFF + 102400;        // 9*1024 [k][pos]
constexpr int WT5_OFF  = WT4_OFF + 9216;          // 9*1024
constexpr int WT6_OFF  = WT5_OFF + 9216;          // 9*256
constexpr int FCWT_OFF = WT6_OFF + 2304;          // [kq][row] float4 = 262144 floats

constexpr int NREP = 136;   // repack blocks prepended to the s1 grid

// ---------------------------------------------------------------------------
// K1: blocks [0,NREP): repack weights (contiguous reads, scattered writes).
//     blocks [NREP,NREP+1024): stage-1 LC conv 7x7 pad 3 -> raw ReLU t1.
// ---------------------------------------------------------------------------
__global__ __launch_bounds__(256) void s1_conv(const float* __restrict__ x,
                                               const float* __restrict__ w1,
                                               const float* __restrict__ b1,
                                               const float* __restrict__ w2,
                                               const float* __restrict__ w3,
                                               const float* __restrict__ w4,
                                               const float* __restrict__ w5,
                                               const float* __restrict__ w6,
                                               const float* __restrict__ fcw,
                                               float* __restrict__ ws)
{
    const int tid = threadIdx.x;

    if (blockIdx.x < NREP) {
        const int rb = blockIdx.x;
        if (rb < 32) {              // w2 -> wT2v: float4[o] at (k*1024+t), p=t+1024o
            for (int idx = rb * 256 + tid; idx < 102400; idx += 32 * 256) {
                int p = idx / 25, k = idx % 25;
                int t = p & 1023, o = p >> 10;
                ws[WT2_OFF + (k * 1024 + t) * 4 + o] = w2[idx];
            }
        } else if (rb < 64) {       // w3 -> wT3v
            for (int idx = (rb - 32) * 256 + tid; idx < 102400; idx += 32 * 256) {
                int p = idx / 25, k = idx % 25;
                int t = p & 1023, o = p >> 10;
                ws[WT3_OFF + (k * 1024 + t) * 4 + o] = w3[idx];
            }
        } else if (rb < 68) {       // w4 -> wT4  [9][1024]
            for (int idx = (rb - 64) * 256 + tid; idx < 9216; idx += 4 * 256) {
                int p = idx / 9, k = idx % 9;
                ws[WT4_OFF + k * 1024 + p] = w4[idx];
            }
        } else if (rb < 72) {       // w5 -> wT5
            for (int idx = (rb - 68) * 256 + tid; idx < 9216; idx += 4 * 256) {
                int p = idx / 9, k = idx % 9;
                ws[WT5_OFF + k * 1024 + p] = w5[idx];
            }
        } else if (rb < 73) {       // w6 -> wT6  [9][256]
            for (int idx = tid; idx < 2304; idx += 256) {
                int p = idx / 9, k = idx % 9;
                ws[WT6_OFF + k * 256 + p] = w6[idx];
            }
        } else {                    // fcw [1024,256] -> fcwT4 [kq][row][4]
            for (int idx = (rb - 73) * 256 + tid; idx < 262144; idx += 63 * 256) {
                int r = idx >> 8, kc = idx & 255;
                int kq = kc >> 2, c = kc & 3;
                ws[FCWT_OFF + kq * 4096 + r * 4 + c] = fcw[idx];
            }
        }
        return;
    }

    // ---- stage-1 conv: 8x8 tile x 16 samples ----
    constexpr int R = 128, K = 7, TILE = 8, S = 16, PAD = 3;
    constexpr int RT = TILE + K - 1;
    constexpr int PP = RT * RT + 1;
    constexpr int NBLK = R / TILE;
    constexpr int WCNT = TILE * TILE * K * K;
    constexpr int PG = 256 / S;
    constexpr int OPT = TILE * TILE / PG;

    __shared__ float s_in[S * PP];
    __shared__ float s_w[WCNT];
    __shared__ float s_b[TILE * TILE];

    float* t1 = ws + T1_OFF;
    const int cb = blockIdx.x - NREP;
    const int bt = cb % (NBLK * NBLK);
    const int sg = cb / (NBLK * NBLK);
    const int i0 = (bt / NBLK) * TILE;
    const int j0 = (bt % NBLK) * TILE;
    const int S0 = sg * S;

    for (int idx = tid; idx < WCNT; idx += 256) {
        int pi = idx / (K * K), kk = idx % (K * K);
        int gi = i0 + pi / TILE, gj = j0 + pi % TILE;
        s_w[idx] = w1[(gi * R + gj) * (K * K) + kk];
    }
    if (tid < TILE * TILE)
        s_b[tid] = b1[(i0 + tid / TILE) * R + (j0 + tid % TILE)];

    for (int idx = tid; idx < S * RT * RT; idx += 256) {
        int ls = idx / (RT * RT), p = idx % (RT * RT);
        int ci = i0 - PAD + p / RT, cj = j0 - PAD + p % RT;
        float v = 0.0f;
        if (ci >= 0 && ci < R && cj >= 0 && cj < R)
            v = x[(S0 + ls) * R * R + ci * R + cj];
        s_in[ls * PP + p] = v;
    }
    __syncthreads();

    const int s = tid % S;
    const int pg = tid / S;
    const int p0 = pg * OPT;
    const int ti = p0 / TILE, tj0 = p0 % TILE;
    float acc[OPT];
    #pragma unroll
    for (int o = 0; o < OPT; o++) acc[o] = s_b[p0 + o];
    #pragma unroll
    for (int ki = 0; ki < K; ki++) {
        float row[OPT + K - 1];
        #pragma unroll
        for (int c = 0; c < OPT + K - 1; c++)
            row[c] = s_in[s * PP + (ti + ki) * RT + tj0 + c];
        #pragma unroll
        for (int kj = 0; kj < K; kj++)
            #pragma unroll
            for (int o = 0; o < OPT; o++)
                acc[o] += row[o + kj] * s_w[(p0 + o) * (K * K) + ki * K + kj];
    }
    #pragma unroll
    for (int o = 0; o < OPT; o++)
        t1[(S0 + s) * R * R + (i0 + ti) * R + (j0 + tj0 + o)] = fmaxf(acc[o], 0.0f);
}

// ---------------------------------------------------------------------------
// K2 — NT = 1024 threads, one block per sample. Odd LDS strides (65/33/17).
// ---------------------------------------------------------------------------
constexpr int NT = 1024;
constexpr int NW = NT / 64;

__device__ __forceinline__ void stats_reduce(float* red, float lsum, float lsq,
                                             float inv_n, float* s_mu, float* s_rs)
{
    const int tid = threadIdx.x;
    #pragma unroll
    for (int off = 32; off > 0; off >>= 1) {
        lsum += __shfl_down(lsum, off, 64);
        lsq  += __shfl_down(lsq,  off, 64);
    }
    if ((tid & 63) == 0) { red[tid >> 6] = lsum; red[NW + (tid >> 6)] = lsq; }
    __syncthreads();
    if (tid == 0) {
        float a = 0.f, b = 0.f;
        #pragma unroll
        for (int i = 0; i < NW; i++) { a += red[i]; b += red[NW + i]; }
        float mu = a * inv_n, ms = b * inv_n;
        *s_mu = mu;
        *s_rs = rsqrtf(ms - mu * mu + LN_EPS);
    }
    __syncthreads();
}

// conv 5x5 over 64x64 (stride 65). Thread owns positions p = tid + o*1024
// (o=0..3) — identical mapping, LDS addresses/order, and accumulation order
// as r10's conv_lds<64,5>; only the weight loads change: 25 float4 (quad-
// packed over o) instead of 100 scalars.
__device__ __forceinline__ void conv64_5v(const float* __restrict__ I,
                                          const float* __restrict__ wTv,
                                          const float* __restrict__ bias,
                                          float* __restrict__ R,
                                          float& lsum, float& lsq)
{
    const int tid = threadIdx.x;
    const int i0 = tid >> 6;        // row of p at o=0; row at o = i0 + 16*o
    const int j  = tid & 63;
    float acc[4];
    #pragma unroll
    for (int o = 0; o < 4; o++) acc[o] = bias[tid + o * NT];

    #pragma unroll
    for (int ki = 0; ki < 5; ki++) {
        #pragma unroll
        for (int kj = 0; kj < 5; kj++) {
            float4 wv = *(const float4*)(wTv + ((ki * 5 + kj) * 1024 + tid) * 4);
            const float w0 = wv.x, w1 = wv.y, w2 = wv.z, w3 = wv.w;
            int jj = j - 2 + kj;
            bool cok = (jj >= 0 && jj < 64);
            #pragma unroll
            for (int o = 0; o < 4; o++) {
                int ii = i0 + 16 * o - 2 + ki;
                float iv = (cok && ii >= 0 && ii < 64) ? I[ii * 65 + jj] : 0.0f;
                acc[o] += iv * (o == 0 ? w0 : o == 1 ? w1 : o == 2 ? w2 : w3);
            }
        }
    }
    #pragma unroll
    for (int o = 0; o < 4; o++) {
        int p = tid + o * NT;
        int i = p >> 6;
        float v = fmaxf(acc[o], 0.0f);
        R[i * 65 + j] = v;
        lsum += v;
        lsq  += v * v;
    }
}

// conv KxK over M x M LDS map (stride M+1), one position per thread (M<=32).
template<int M, int K>
__device__ __forceinline__ void conv_lds(const float* __restrict__ I,
                                         const float* __restrict__ wT,
                                         const float* __restrict__ bias,
                                         float* __restrict__ R,
                                         float& lsum, float& lsq)
{
    constexpr int NPOS = M * M;
    constexpr int PADK = (K - 1) / 2;
    constexpr int STR = M + 1;
    const int tid = threadIdx.x;
    if (NPOS < NT && tid >= NPOS) return;
    int i = tid / M, j = tid % M;
    float acc = bias[tid];
    #pragma unroll
    for (int ki = 0; ki < K; ki++) {
        int ii = i - PADK + ki;
        bool rok = (ii >= 0 && ii < M);
        #pragma unroll
        for (int kj = 0; kj < K; kj++) {
            int jj = j - PADK + kj;
            float iv = (rok && jj >= 0 && jj < M) ? I[ii * STR + jj] : 0.0f;
            acc += iv * wT[(ki * K + kj) * NPOS + tid];
        }
    }
    float v = fmaxf(acc, 0.0f);
    R[i * STR + j] = v;
    lsum += v;
    lsq  += v * v;
}

// LN (+ optional 2x2 maxpool) of raw map R (res N, stride N+1) -> I (res M).
template<int N, bool POOL>
__device__ __forceinline__ void transform(const float* __restrict__ R,
                                          float mu, float rs,
                                          const float* __restrict__ g,
                                          const float* __restrict__ b,
                                          float* __restrict__ I)
{
    constexpr int M = POOL ? N / 2 : N;
    constexpr int SR = N + 1, SI = M + 1;
    const int tid = threadIdx.x;
    for (int p = tid; p < M * M; p += NT) {
        int i = p / M, j = p % M;
        float v;
        if constexpr (POOL) {
            float best = -3.4e38f;
            #pragma unroll
            for (int dy = 0; dy < 2; dy++)
                #pragma unroll
                for (int dx = 0; dx < 2; dx++) {
                    int r = 2 * i + dy, c = 2 * j + dx;
                    float n = (R[r * SR + c] - mu) * rs * g[r * N + c] + b[r * N + c];
                    best = fmaxf(best, n);
                }
            v = best;
        } else {
            v = (R[i * SR + j] - mu) * rs * g[i * N + j] + b[i * N + j];
        }
        I[i * SI + j] = v;
    }
}

// ---------------------------------------------------------------------------
// K2: stages 2-6 + FC + softmax. One block (1024 thr) per sample.
// ---------------------------------------------------------------------------
__global__ __launch_bounds__(1024) void tail_fused(
    const float* __restrict__ ws_ro,
    const float* __restrict__ g1, const float* __restrict__ be1,
    const float* __restrict__ b2,
    const float* __restrict__ g2, const float* __restrict__ be2,
    const float* __restrict__ b3,
    const float* __restrict__ g3, const float* __restrict__ be3,
    const float* __restrict__ b4,
    const float* __restrict__ g4, const float* __restrict__ be4,
    const float* __restrict__ b5,
    const float* __restrict__ g5, const float* __restrict__ be5,
    const float* __restrict__ b6,
    const float* __restrict__ g6, const float* __restrict__ be6,
    const float* __restrict__ fcb,
    float* __restrict__ outp)
{
    __shared__ __align__(16) float I[64 * 65];
    __shared__ __align__(16) float R[64 * 65];
    __shared__ __align__(16) float h[256];
    __shared__ float red[2 * NW];
    __shared__ float s_mu, s_rs;

    const int s = blockIdx.x;
    const int tid = threadIdx.x;
    const float* x1  = ws_ro + T1_OFF + s * 16384;
    const float* wT2 = ws_ro + WT2_OFF;
    const float* wT3 = ws_ro + WT3_OFF;
    const float* wT4 = ws_ro + WT4_OFF;
    const float* wT5 = ws_ro + WT5_OFF;
    const float* wT6 = ws_ro + WT6_OFF;

    // LN1 stats over raw stage-1 output (float4)
    float ls = 0.f, lq = 0.f;
    {
        const float4* x4 = (const float4*)x1;
        #pragma unroll
        for (int i = tid; i < 4096; i += NT) {
            float4 v = x4[i];
            ls += v.x + v.y + v.z + v.w;
            lq += v.x * v.x + v.y * v.y + v.z * v.z + v.w * v.w;
        }
    }
    stats_reduce(red, ls, lq, 1.f / 16384.f, &s_mu, &s_rs);

    // pool(LN1(t1)) -> I (64x64, stride 65). float2 loads, lane-consecutive.
    {
        float mu = s_mu, rs = s_rs;
        #pragma unroll
        for (int o = 0; o < 4; o++) {
            int p = tid + o * NT;
            int i = p >> 6, j = p & 63;
            float2 xa = *((const float2*)(x1 + (2 * i) * 128 + 2 * j));
            float2 xb = *((const float2*)(x1 + (2 * i + 1) * 128 + 2 * j));
            float2 ga = *((const float2*)(g1 + (2 * i) * 128 + 2 * j));
            float2 gb = *((const float2*)(g1 + (2 * i + 1) * 128 + 2 * j));
            float2 ba = *((const float2*)(be1 + (2 * i) * 128 + 2 * j));
            float2 bb = *((const float2*)(be1 + (2 * i + 1) * 128 + 2 * j));
            float n0 = (xa.x - mu) * rs * ga.x + ba.x;
            float n1 = (xa.y - mu) * rs * ga.y + ba.y;
            float n2 = (xb.x - mu) * rs * gb.x + bb.x;
            float n3 = (xb.y - mu) * rs * gb.y + bb.y;
            I[i * 65 + j] = fmaxf(fmaxf(n0, n1), fmaxf(n2, n3));
        }
    }
    __syncthreads();

    // S2: conv5 -> R, LN2
    ls = lq = 0.f; conv64_5v(I, wT2, b2, R, ls, lq);
    stats_reduce(red, ls, lq, 1.f / 4096.f, &s_mu, &s_rs);
    transform<64, false>(R, s_mu, s_rs, g2, be2, I);
    __syncthreads();

    // S3: conv5 -> R, LN3, pool -> 32
    ls = lq = 0.f; conv64_5v(I, wT3, b3, R, ls, lq);
    stats_reduce(red, ls, lq, 1.f / 4096.f, &s_mu, &s_rs);
    transform<64, true>(R, s_mu, s_rs, g3, be3, I);
    __syncthreads();

    // S4: conv3 (32) -> R, LN4
    ls = lq = 0.f; conv_lds<32, 3>(I, wT4, b4, R, ls, lq);
    stats_reduce(red, ls, lq, 1.f / 1024.f, &s_mu, &s_rs);
    transform<32, false>(R, s_mu, s_rs, g4, be4, I);
    __syncthreads();

    // S5: conv3 (32) -> R, LN5, pool -> 16
    ls = lq = 0.f; conv_lds<32, 3>(I, wT5, b5, R, ls, lq);
    stats_reduce(red, ls, lq, 1.f / 1024.f, &s_mu, &s_rs);
    transform<32, true>(R, s_mu, s_rs, g5, be5, I);
    __syncthreads();

    // S6: conv3 (16) -> R, LN6
    ls = lq = 0.f; conv_lds<16, 3>(I, wT6, b6, R, ls, lq);
    stats_reduce(red, ls, lq, 1.f / 256.f, &s_mu, &s_rs);

    // LN6 -> h[256]
    if (tid < 256) {
        int i = tid >> 4, j = tid & 15;
        h[tid] = (R[i * 17 + j] - s_mu) * s_rs * g6[tid] + be6[tid];
    }
    __syncthreads();

    // FC 256->1024: one logit/thread, 64 coalesced float4 weight loads.
    float acc = fcb[tid];
    {
        const float4* wq = (const float4*)(ws_ro + FCWT_OFF);
        const float4* h4 = (const float4*)h;
        #pragma unroll 8
        for (int kq = 0; kq < 64; kq++) {
            float4 wv = wq[kq * 1024 + tid];
            float4 hv = h4[kq];
            acc += wv.x * hv.x + wv.y * hv.y + wv.z * hv.z + wv.w * hv.w;
        }
    }

    // softmax over the block's 1024 logits
    float m = acc;
    #pragma unroll
    for (int off = 32; off > 0; off >>= 1)
        m = fmaxf(m, __shfl_down(m, off, 64));
    if ((tid & 63) == 0) red[tid >> 6] = m;
    __syncthreads();
    if (tid == 0) {
        float mm = red[0];
        #pragma unroll
        for (int i = 1; i < NW; i++) mm = fmaxf(mm, red[i]);
        s_mu = mm;
    }
    __syncthreads();
    float e = expf(acc - s_mu);
    float sum = e;
    #pragma unroll
    for (int off = 32; off > 0; off >>= 1)
        sum += __shfl_down(sum, off, 64);
    if ((tid & 63) == 0) red[NW + (tid >> 6)] = sum;
    __syncthreads();
    if (tid == 0) {
        float ss = 0.f;
        #pragma unroll
        for (int i = 0; i < NW; i++) ss += red[NW + i];
        s_rs = 1.0f / ss;
    }
    __syncthreads();
    outp[s * 1024 + tid] = e * s_rs;
}

// ---------------------------------------------------------------------------
extern "C" void kernel_launch(void* const* d_in, const int* in_sizes, int n_in,
                              void* d_out, int out_size, void* d_ws, size_t ws_size,
                              hipStream_t stream) {
    (void)in_sizes; (void)n_in; (void)out_size; (void)ws_size;

    const float* x   = (const float*)d_in[0];
    const float* w1  = (const float*)d_in[1];  const float* b1  = (const float*)d_in[2];
    const float* g1  = (const float*)d_in[3];  const float* be1 = (const float*)d_in[4];
    const float* w2  = (const float*)d_in[5];  const float* b2  = (const float*)d_in[6];
    const float* g2  = (const float*)d_in[7];  const float* be2 = (const float*)d_in[8];
    const float* w3  = (const float*)d_in[9];  const float* b3  = (const float*)d_in[10];
    const float* g3  = (const float*)d_in[11]; const float* be3 = (const float*)d_in[12];
    const float* w4  = (const float*)d_in[13]; const float* b4  = (const float*)d_in[14];
    const float* g4  = (const float*)d_in[15]; const float* be4 = (const float*)d_in[16];
    const float* w5  = (const float*)d_in[17]; const float* b5  = (const float*)d_in[18];
    const float* g5  = (const float*)d_in[19]; const float* be5 = (const float*)d_in[20];
    const float* w6  = (const float*)d_in[21]; const float* b6  = (const float*)d_in[22];
    const float* g6  = (const float*)d_in[23]; const float* be6 = (const float*)d_in[24];
    const float* fcw = (const float*)d_in[25]; const float* fcb = (const float*)d_in[26];

    float* ws = (float*)d_ws;

    s1_conv<<<NREP + 1024, 256, 0, stream>>>(x, w1, b1, w2, w3, w4, w5, w6, fcw, ws);
    tail_fused<<<64, 1024, 0, stream>>>((const float*)ws,
        g1, be1, b2, g2, be2, b3, g3, be3,
        b4, g4, be4, b5, g5, be5, b6, g6, be6,
        fcb, (float*)d_out);
}

// Round 13
// 161.853 us; speedup vs baseline: 1.4622x; 1.4622x over previous
//
#include <hip/hip_runtime.h>

#define LN_EPS 1e-5f

// ---------------------------------------------------------------------------
// ws layout (floats)
// ---------------------------------------------------------------------------
constexpr int T1_OFF   = 0;                       // 64*128*128 = 1048576
constexpr int WT2_OFF  = 1048576;                 // 25*4096 [k][pos]
constexpr int WT3_OFF  = WT2_OFF + 102400;        // 25*4096
constexpr int WT4_OFF  = WT3_OFF + 102400;        // 9*1024
constexpr int WT5_OFF  = WT4_OFF + 9216;          // 9*1024
constexpr int WT6_OFF  = WT5_OFF + 9216;          // 9*256
constexpr int FCWT_OFF = WT6_OFF + 2304;          // [kq][row] float4 = 262144 floats
constexpr int ST_OFF   = FCWT_OFF + 262144;       // LN1 stats: sum[64], sumsq[64]

constexpr int NREP = 136;   // repack blocks prepended to the s1 grid

// ---------------------------------------------------------------------------
// K1: blocks [0,NREP): repack weights (contiguous reads, scattered writes).
//     blocks [NREP,NREP+1024): stage-1 LC conv 7x7 pad 3 -> raw ReLU t1,
//     accumulating per-sample LN1 (sum,sumsq) via block reduction + atomics
//     (r1/r2-proven pattern).
// ---------------------------------------------------------------------------
__global__ __launch_bounds__(256) void s1_conv(const float* __restrict__ x,
                                               const float* __restrict__ w1,
                                               const float* __restrict__ b1,
                                               const float* __restrict__ w2,
                                               const float* __restrict__ w3,
                                               const float* __restrict__ w4,
                                               const float* __restrict__ w5,
                                               const float* __restrict__ w6,
                                               const float* __restrict__ fcw,
                                               float* __restrict__ ws)
{
    const int tid = threadIdx.x;

    if (blockIdx.x < NREP) {
        const int rb = blockIdx.x;
        if (rb < 32) {              // w2 -> wT2  [25][4096]
            for (int idx = rb * 256 + tid; idx < 102400; idx += 32 * 256) {
                int p = idx / 25, k = idx % 25;
                ws[WT2_OFF + k * 4096 + p] = w2[idx];
            }
        } else if (rb < 64) {       // w3 -> wT3
            for (int idx = (rb - 32) * 256 + tid; idx < 102400; idx += 32 * 256) {
                int p = idx / 25, k = idx % 25;
                ws[WT3_OFF + k * 4096 + p] = w3[idx];
            }
        } else if (rb < 68) {       // w4 -> wT4  [9][1024]
            for (int idx = (rb - 64) * 256 + tid; idx < 9216; idx += 4 * 256) {
                int p = idx / 9, k = idx % 9;
                ws[WT4_OFF + k * 1024 + p] = w4[idx];
            }
        } else if (rb < 72) {       // w5 -> wT5
            for (int idx = (rb - 68) * 256 + tid; idx < 9216; idx += 4 * 256) {
                int p = idx / 9, k = idx % 9;
                ws[WT5_OFF + k * 1024 + p] = w5[idx];
            }
        } else if (rb < 73) {       // w6 -> wT6  [9][256]
            for (int idx = tid; idx < 2304; idx += 256) {
                int p = idx / 9, k = idx % 9;
                ws[WT6_OFF + k * 256 + p] = w6[idx];
            }
        } else {                    // fcw [1024,256] -> fcwT4 [kq][row][4]
            for (int idx = (rb - 73) * 256 + tid; idx < 262144; idx += 63 * 256) {
                int r = idx >> 8, kc = idx & 255;
                int kq = kc >> 2, c = kc & 3;
                ws[FCWT_OFF + kq * 4096 + r * 4 + c] = fcw[idx];
            }
        }
        return;
    }

    // ---- stage-1 conv: 8x8 tile x 16 samples ----
    constexpr int R = 128, K = 7, TILE = 8, S = 16, PAD = 3;
    constexpr int RT = TILE + K - 1;
    constexpr int PP = RT * RT + 1;
    constexpr int NBLK = R / TILE;
    constexpr int WCNT = TILE * TILE * K * K;
    constexpr int PG = 256 / S;
    constexpr int OPT = TILE * TILE / PG;

    __shared__ float s_in[S * PP];
    __shared__ float s_w[WCNT];          // reused as reduction buffer at the end
    __shared__ float s_b[TILE * TILE];

    float* t1 = ws + T1_OFF;
    const int cb = blockIdx.x - NREP;
    const int bt = cb % (NBLK * NBLK);
    const int sg = cb / (NBLK * NBLK);
    const int i0 = (bt / NBLK) * TILE;
    const int j0 = (bt % NBLK) * TILE;
    const int S0 = sg * S;

    for (int idx = tid; idx < WCNT; idx += 256) {
        int pi = idx / (K * K), kk = idx % (K * K);
        int gi = i0 + pi / TILE, gj = j0 + pi % TILE;
        s_w[idx] = w1[(gi * R + gj) * (K * K) + kk];
    }
    if (tid < TILE * TILE)
        s_b[tid] = b1[(i0 + tid / TILE) * R + (j0 + tid % TILE)];

    for (int idx = tid; idx < S * RT * RT; idx += 256) {
        int ls = idx / (RT * RT), p = idx % (RT * RT);
        int ci = i0 - PAD + p / RT, cj = j0 - PAD + p % RT;
        float v = 0.0f;
        if (ci >= 0 && ci < R && cj >= 0 && cj < R)
            v = x[(S0 + ls) * R * R + ci * R + cj];
        s_in[ls * PP + p] = v;
    }
    __syncthreads();

    const int s = tid % S;
    const int pg = tid / S;
    const int p0 = pg * OPT;
    const int ti = p0 / TILE, tj0 = p0 % TILE;
    float acc[OPT];
    #pragma unroll
    for (int o = 0; o < OPT; o++) acc[o] = s_b[p0 + o];
    #pragma unroll
    for (int ki = 0; ki < K; ki++) {
        float row[OPT + K - 1];
        #pragma unroll
        for (int c = 0; c < OPT + K - 1; c++)
            row[c] = s_in[s * PP + (ti + ki) * RT + tj0 + c];
        #pragma unroll
        for (int kj = 0; kj < K; kj++)
            #pragma unroll
            for (int o = 0; o < OPT; o++)
                acc[o] += row[o + kj] * s_w[(p0 + o) * (K * K) + ki * K + kj];
    }
    float lsum = 0.f, lsq = 0.f;
    #pragma unroll
    for (int o = 0; o < OPT; o++) {
        float v = fmaxf(acc[o], 0.0f);
        t1[(S0 + s) * R * R + (i0 + ti) * R + (j0 + tj0 + o)] = v;
        lsum += v;
        lsq  += v * v;
    }

    // per-sample LN1 stats: block reduction (reuse s_w), then atomics
    __syncthreads();
    s_w[tid]       = lsum;
    s_w[256 + tid] = lsq;
    __syncthreads();
    if (tid < S) {
        float a = 0.f, b = 0.f;
        #pragma unroll
        for (int g = 0; g < PG; g++) {
            a += s_w[g * S + tid];
            b += s_w[256 + g * S + tid];
        }
        atomicAdd(&ws[ST_OFF + S0 + tid], a);
        atomicAdd(&ws[ST_OFF + 64 + S0 + tid], b);
    }
}

// ---------------------------------------------------------------------------
// K2 — NT = 1024 threads, one block per sample. Odd LDS strides (65/33/17).
// ---------------------------------------------------------------------------
constexpr int NT = 1024;
constexpr int NW = NT / 64;

__device__ __forceinline__ void stats_reduce(float* red, float lsum, float lsq,
                                             float inv_n, float* s_mu, float* s_rs)
{
    const int tid = threadIdx.x;
    #pragma unroll
    for (int off = 32; off > 0; off >>= 1) {
        lsum += __shfl_down(lsum, off, 64);
        lsq  += __shfl_down(lsq,  off, 64);
    }
    if ((tid & 63) == 0) { red[tid >> 6] = lsum; red[NW + (tid >> 6)] = lsq; }
    __syncthreads();
    if (tid == 0) {
        float a = 0.f, b = 0.f;
        #pragma unroll
        for (int i = 0; i < NW; i++) { a += red[i]; b += red[NW + i]; }
        float mu = a * inv_n, ms = b * inv_n;
        *s_mu = mu;
        *s_rs = rsqrtf(ms - mu * mu + LN_EPS);
    }
    __syncthreads();
}

// conv KxK over M x M LDS map (stride M+1) -> ReLU into R, accumulating
// sum/sumsq. Weights [k][NPOS], lane-consecutive p -> coalesced reads.
template<int M, int K>
__device__ __forceinline__ void conv_lds(const float* __restrict__ I,
                                         const float* __restrict__ wT,
                                         const float* __restrict__ bias,
                                         float* __restrict__ R,
                                         float& lsum, float& lsq)
{
    constexpr int NPOS = M * M;
    constexpr int PADK = (K - 1) / 2;
    constexpr int STR = M + 1;
    constexpr int OPT = (NPOS + NT - 1) / NT;
    const int tid = threadIdx.x;

    #pragma unroll
    for (int o = 0; o < OPT; o++) {
        int p = tid + o * NT;
        if (NPOS < NT && p >= NPOS) break;
        int i = p / M, j = p % M;
        float acc = bias[p];
        #pragma unroll
        for (int ki = 0; ki < K; ki++) {
            int ii = i - PADK + ki;
            bool rok = (ii >= 0 && ii < M);
            #pragma unroll
            for (int kj = 0; kj < K; kj++) {
                int jj = j - PADK + kj;
                float iv = (rok && jj >= 0 && jj < M) ? I[ii * STR + jj] : 0.0f;
                acc += iv * wT[(ki * K + kj) * NPOS + p];
            }
        }
        float v = fmaxf(acc, 0.0f);
        R[i * STR + j] = v;
        lsum += v;
        lsq  += v * v;
    }
}

// LN (+ optional 2x2 maxpool) of raw map R (res N, stride N+1) -> I (res M).
template<int N, bool POOL>
__device__ __forceinline__ void transform(const float* __restrict__ R,
                                          float mu, float rs,
                                          const float* __restrict__ g,
                                          const float* __restrict__ b,
                                          float* __restrict__ I)
{
    constexpr int M = POOL ? N / 2 : N;
    constexpr int SR = N + 1, SI = M + 1;
    const int tid = threadIdx.x;
    for (int p = tid; p < M * M; p += NT) {
        int i = p / M, j = p % M;
        float v;
        if constexpr (POOL) {
            float best = -3.4e38f;
            #pragma unroll
            for (int dy = 0; dy < 2; dy++)
                #pragma unroll
                for (int dx = 0; dx < 2; dx++) {
                    int r = 2 * i + dy, c = 2 * j + dx;
                    float n = (R[r * SR + c] - mu) * rs * g[r * N + c] + b[r * N + c];
                    best = fmaxf(best, n);
                }
            v = best;
        } else {
            v = (R[i * SR + j] - mu) * rs * g[i * N + j] + b[i * N + j];
        }
        I[i * SI + j] = v;
    }
}

// ---------------------------------------------------------------------------
// K2: stages 2-6 + FC + softmax. One block (1024 thr) per sample.
// ---------------------------------------------------------------------------
__global__ __launch_bounds__(1024) void tail_fused(
    const float* __restrict__ ws_ro,
    const float* __restrict__ g1, const float* __restrict__ be1,
    const float* __restrict__ b2,
    const float* __restrict__ g2, const float* __restrict__ be2,
    const float* __restrict__ b3,
    const float* __restrict__ g3, const float* __restrict__ be3,
    const float* __restrict__ b4,
    const float* __restrict__ g4, const float* __restrict__ be4,
    const float* __restrict__ b5,
    const float* __restrict__ g5, const float* __restrict__ be5,
    const float* __restrict__ b6,
    const float* __restrict__ g6, const float* __restrict__ be6,
    const float* __restrict__ fcb,
    float* __restrict__ outp)
{
    __shared__ __align__(16) float I[64 * 65];
    __shared__ __align__(16) float R[64 * 65];
    __shared__ __align__(16) float h[256];
    __shared__ float red[2 * NW];
    __shared__ float s_mu, s_rs;

    const int s = blockIdx.x;
    const int tid = threadIdx.x;
    const float* x1  = ws_ro + T1_OFF + s * 16384;
    const float* wT2 = ws_ro + WT2_OFF;
    const float* wT3 = ws_ro + WT3_OFF;
    const float* wT4 = ws_ro + WT4_OFF;
    const float* wT5 = ws_ro + WT5_OFF;
    const float* wT6 = ws_ro + WT6_OFF;

    // LN1 stats from s1's atomically-accumulated (sum, sumsq)
    if (tid == 0) {
        float mu = ws_ro[ST_OFF + s] * (1.f / 16384.f);
        float ms = ws_ro[ST_OFF + 64 + s] * (1.f / 16384.f);
        s_mu = mu;
        s_rs = rsqrtf(ms - mu * mu + LN_EPS);
    }
    __syncthreads();

    // pool(LN1(t1)) -> I (64x64, stride 65). float2 loads, lane-consecutive.
    {
        float mu = s_mu, rs = s_rs;
        #pragma unroll
        for (int o = 0; o < 4; o++) {
            int p = tid + o * NT;
            int i = p >> 6, j = p & 63;
            float2 xa = *((const float2*)(x1 + (2 * i) * 128 + 2 * j));
            float2 xb = *((const float2*)(x1 + (2 * i + 1) * 128 + 2 * j));
            float2 ga = *((const float2*)(g1 + (2 * i) * 128 + 2 * j));
            float2 gb = *((const float2*)(g1 + (2 * i + 1) * 128 + 2 * j));
            float2 ba = *((const float2*)(be1 + (2 * i) * 128 + 2 * j));
            float2 bb = *((const float2*)(be1 + (2 * i + 1) * 128 + 2 * j));
            float n0 = (xa.x - mu) * rs * ga.x + ba.x;
            float n1 = (xa.y - mu) * rs * ga.y + ba.y;
            float n2 = (xb.x - mu) * rs * gb.x + bb.x;
            float n3 = (xb.y - mu) * rs * gb.y + bb.y;
            I[i * 65 + j] = fmaxf(fmaxf(n0, n1), fmaxf(n2, n3));
        }
    }
    __syncthreads();

    float ls, lq;

    // S2: conv5 -> R, LN2
    ls = lq = 0.f; conv_lds<64, 5>(I, wT2, b2, R, ls, lq);
    stats_reduce(red, ls, lq, 1.f / 4096.f, &s_mu, &s_rs);
    transform<64, false>(R, s_mu, s_rs, g2, be2, I);
    __syncthreads();

    // S3: conv5 -> R, LN3, pool -> 32
    ls = lq = 0.f; conv_lds<64, 5>(I, wT3, b3, R, ls, lq);
    stats_reduce(red, ls, lq, 1.f / 4096.f, &s_mu, &s_rs);
    transform<64, true>(R, s_mu, s_rs, g3, be3, I);
    __syncthreads();

    // S4: conv3 (32) -> R, LN4
    ls = lq = 0.f; conv_lds<32, 3>(I, wT4, b4, R, ls, lq);
    stats_reduce(red, ls, lq, 1.f / 1024.f, &s_mu, &s_rs);
    transform<32, false>(R, s_mu, s_rs, g4, be4, I);
    __syncthreads();

    // S5: conv3 (32) -> R, LN5, pool -> 16
    ls = lq = 0.f; conv_lds<32, 3>(I, wT5, b5, R, ls, lq);
    stats_reduce(red, ls, lq, 1.f / 1024.f, &s_mu, &s_rs);
    transform<32, true>(R, s_mu, s_rs, g5, be5, I);
    __syncthreads();

    // S6: conv3 (16) -> R, LN6
    ls = lq = 0.f; conv_lds<16, 3>(I, wT6, b6, R, ls, lq);
    stats_reduce(red, ls, lq, 1.f / 256.f, &s_mu, &s_rs);

    // LN6 -> h[256]
    if (tid < 256) {
        int i = tid >> 4, j = tid & 15;
        h[tid] = (R[i * 17 + j] - s_mu) * s_rs * g6[tid] + be6[tid];
    }
    __syncthreads();

    // FC 256->1024: one logit/thread, 64 coalesced float4 weight loads.
    float acc = fcb[tid];
    {
        const float4* wq = (const float4*)(ws_ro + FCWT_OFF);
        const float4* h4 = (const float4*)h;
        #pragma unroll 8
        for (int kq = 0; kq < 64; kq++) {
            float4 wv = wq[kq * 1024 + tid];
            float4 hv = h4[kq];
            acc += wv.x * hv.x + wv.y * hv.y + wv.z * hv.z + wv.w * hv.w;
        }
    }

    // softmax over the block's 1024 logits
    float m = acc;
    #pragma unroll
    for (int off = 32; off > 0; off >>= 1)
        m = fmaxf(m, __shfl_down(m, off, 64));
    if ((tid & 63) == 0) red[tid >> 6] = m;
    __syncthreads();
    if (tid == 0) {
        float mm = red[0];
        #pragma unroll
        for (int i = 1; i < NW; i++) mm = fmaxf(mm, red[i]);
        s_mu = mm;
    }
    __syncthreads();
    float e = expf(acc - s_mu);
    float sum = e;
    #pragma unroll
    for (int off = 32; off > 0; off >>= 1)
        sum += __shfl_down(sum, off, 64);
    if ((tid & 63) == 0) red[NW + (tid >> 6)] = sum;
    __syncthreads();
    if (tid == 0) {
        float ss = 0.f;
        #pragma unroll
        for (int i = 0; i < NW; i++) ss += red[NW + i];
        s_rs = 1.0f / ss;
    }
    __syncthreads();
    outp[s * 1024 + tid] = e * s_rs;
}

// ---------------------------------------------------------------------------
extern "C" void kernel_launch(void* const* d_in, const int* in_sizes, int n_in,
                              void* d_out, int out_size, void* d_ws, size_t ws_size,
                              hipStream_t stream) {
    (void)in_sizes; (void)n_in; (void)out_size; (void)ws_size;

    const float* x   = (const float*)d_in[0];
    const float* w1  = (const float*)d_in[1];  const float* b1  = (const float*)d_in[2];
    const float* g1  = (const float*)d_in[3];  const float* be1 = (const float*)d_in[4];
    const float* w2  = (const float*)d_in[5];  const float* b2  = (const float*)d_in[6];
    const float* g2  = (const float*)d_in[7];  const float* be2 = (const float*)d_in[8];
    const float* w3  = (const float*)d_in[9];  const float* b3  = (const float*)d_in[10];
    const float* g3  = (const float*)d_in[11]; const float* be3 = (const float*)d_in[12];
    const float* w4  = (const float*)d_in[13]; const float* b4  = (const float*)d_in[14];
    const float* g4  = (const float*)d_in[15]; const float* be4 = (const float*)d_in[16];
    const float* w5  = (const float*)d_in[17]; const float* b5  = (const float*)d_in[18];
    const float* g5  = (const float*)d_in[19]; const float* be5 = (const float*)d_in[20];
    const float* w6  = (const float*)d_in[21]; const float* b6  = (const float*)d_in[22];
    const float* g6  = (const float*)d_in[23]; const float* be6 = (const float*)d_in[24];
    const float* fcw = (const float*)d_in[25]; const float* fcb = (const float*)d_in[26];

    float* ws = (float*)d_ws;

    hipMemsetAsync(ws + ST_OFF, 0, 128 * sizeof(float), stream);
    s1_conv<<<NREP + 1024, 256, 0, stream>>>(x, w1, b1, w2, w3, w4, w5, w6, fcw, ws);
    tail_fused<<<64, 1024, 0, stream>>>((const float*)ws,
        g1, be1, b2, g2, be2, b3, g3, be3,
        b4, g4, be4, b5, g5, be5, b6, g6, be6,
        fcb, (float*)d_out);
}

// Round 14
// 154.301 us; speedup vs baseline: 1.5338x; 1.0489x over previous
//
#include <hip/hip_runtime.h>

#define LN_EPS 1e-5f

// ---------------------------------------------------------------------------
// ws layout (floats)
// ---------------------------------------------------------------------------
constexpr int T1_OFF   = 0;                       // 64*128*128 = 1048576
constexpr int WT2_OFF  = 1048576;                 // 25*4096 [k][pos]
constexpr int WT3_OFF  = WT2_OFF + 102400;        // 25*4096
constexpr int WT4_OFF  = WT3_OFF + 102400;        // 9*1024
constexpr int WT5_OFF  = WT4_OFF + 9216;          // 9*1024
constexpr int WT6_OFF  = WT5_OFF + 9216;          // 9*256
constexpr int FCWT_OFF = WT6_OFF + 2304;          // [kq][row] float4 = 262144 floats

constexpr int NREP = 136;   // repack blocks prepended to the s1 grid

// ---------------------------------------------------------------------------
// K1: blocks [0,NREP): repack weights (contiguous reads, scattered writes).
//     blocks [NREP,NREP+1024): stage-1 LC conv 7x7 pad 3 -> raw ReLU t1.
// ---------------------------------------------------------------------------
__global__ __launch_bounds__(256) void s1_conv(const float* __restrict__ x,
                                               const float* __restrict__ w1,
                                               const float* __restrict__ b1,
                                               const float* __restrict__ w2,
                                               const float* __restrict__ w3,
                                               const float* __restrict__ w4,
                                               const float* __restrict__ w5,
                                               const float* __restrict__ w6,
                                               const float* __restrict__ fcw,
                                               float* __restrict__ ws)
{
    const int tid = threadIdx.x;

    if (blockIdx.x < NREP) {
        const int rb = blockIdx.x;
        if (rb < 32) {              // w2 -> wT2  [25][4096]
            for (int idx = rb * 256 + tid; idx < 102400; idx += 32 * 256) {
                int p = idx / 25, k = idx % 25;
                ws[WT2_OFF + k * 4096 + p] = w2[idx];
            }
        } else if (rb < 64) {       // w3 -> wT3
            for (int idx = (rb - 32) * 256 + tid; idx < 102400; idx += 32 * 256) {
                int p = idx / 25, k = idx % 25;
                ws[WT3_OFF + k * 4096 + p] = w3[idx];
            }
        } else if (rb < 68) {       // w4 -> wT4  [9][1024]
            for (int idx = (rb - 64) * 256 + tid; idx < 9216; idx += 4 * 256) {
                int p = idx / 9, k = idx % 9;
                ws[WT4_OFF + k * 1024 + p] = w4[idx];
            }
        } else if (rb < 72) {       // w5 -> wT5
            for (int idx = (rb - 68) * 256 + tid; idx < 9216; idx += 4 * 256) {
                int p = idx / 9, k = idx % 9;
                ws[WT5_OFF + k * 1024 + p] = w5[idx];
            }
        } else if (rb < 73) {       // w6 -> wT6  [9][256]
            for (int idx = tid; idx < 2304; idx += 256) {
                int p = idx / 9, k = idx % 9;
                ws[WT6_OFF + k * 256 + p] = w6[idx];
            }
        } else {                    // fcw [1024,256] -> fcwT4 [kq][row][4]
            for (int idx = (rb - 73) * 256 + tid; idx < 262144; idx += 63 * 256) {
                int r = idx >> 8, kc = idx & 255;
                int kq = kc >> 2, c = kc & 3;
                ws[FCWT_OFF + kq * 4096 + r * 4 + c] = fcw[idx];
            }
        }
        return;
    }

    // ---- stage-1 conv: 8x8 tile x 16 samples ----
    constexpr int R = 128, K = 7, TILE = 8, S = 16, PAD = 3;
    constexpr int RT = TILE + K - 1;
    constexpr int PP = RT * RT + 1;
    constexpr int NBLK = R / TILE;
    constexpr int WCNT = TILE * TILE * K * K;
    constexpr int PG = 256 / S;
    constexpr int OPT = TILE * TILE / PG;

    __shared__ float s_in[S * PP];
    __shared__ float s_w[WCNT];
    __shared__ float s_b[TILE * TILE];

    float* t1 = ws + T1_OFF;
    const int cb = blockIdx.x - NREP;
    const int bt = cb % (NBLK * NBLK);
    const int sg = cb / (NBLK * NBLK);
    const int i0 = (bt / NBLK) * TILE;
    const int j0 = (bt % NBLK) * TILE;
    const int S0 = sg * S;

    for (int idx = tid; idx < WCNT; idx += 256) {
        int pi = idx / (K * K), kk = idx % (K * K);
        int gi = i0 + pi / TILE, gj = j0 + pi % TILE;
        s_w[idx] = w1[(gi * R + gj) * (K * K) + kk];
    }
    if (tid < TILE * TILE)
        s_b[tid] = b1[(i0 + tid / TILE) * R + (j0 + tid % TILE)];

    for (int idx = tid; idx < S * RT * RT; idx += 256) {
        int ls = idx / (RT * RT), p = idx % (RT * RT);
        int ci = i0 - PAD + p / RT, cj = j0 - PAD + p % RT;
        float v = 0.0f;
        if (ci >= 0 && ci < R && cj >= 0 && cj < R)
            v = x[(S0 + ls) * R * R + ci * R + cj];
        s_in[ls * PP + p] = v;
    }
    __syncthreads();

    const int s = tid % S;
    const int pg = tid / S;
    const int p0 = pg * OPT;
    const int ti = p0 / TILE, tj0 = p0 % TILE;
    float acc[OPT];
    #pragma unroll
    for (int o = 0; o < OPT; o++) acc[o] = s_b[p0 + o];
    #pragma unroll
    for (int ki = 0; ki < K; ki++) {
        float row[OPT + K - 1];
        #pragma unroll
        for (int c = 0; c < OPT + K - 1; c++)
            row[c] = s_in[s * PP + (ti + ki) * RT + tj0 + c];
        #pragma unroll
        for (int kj = 0; kj < K; kj++)
            #pragma unroll
            for (int o = 0; o < OPT; o++)
                acc[o] += row[o + kj] * s_w[(p0 + o) * (K * K) + ki * K + kj];
    }
    #pragma unroll
    for (int o = 0; o < OPT; o++)
        t1[(S0 + s) * R * R + (i0 + ti) * R + (j0 + tj0 + o)] = fmaxf(acc[o], 0.0f);
}

// ---------------------------------------------------------------------------
// K2 — NT = 1024 threads, one block per sample. Odd LDS strides (65/33/17).
// ---------------------------------------------------------------------------
constexpr int NT = 1024;
constexpr int NW = NT / 64;

__device__ __forceinline__ void stats_reduce(float* red, float lsum, float lsq,
                                             float inv_n, float* s_mu, float* s_rs)
{
    const int tid = threadIdx.x;
    #pragma unroll
    for (int off = 32; off > 0; off >>= 1) {
        lsum += __shfl_down(lsum, off, 64);
        lsq  += __shfl_down(lsq,  off, 64);
    }
    if ((tid & 63) == 0) { red[tid >> 6] = lsum; red[NW + (tid >> 6)] = lsq; }
    __syncthreads();
    if (tid == 0) {
        float a = 0.f, b = 0.f;
        #pragma unroll
        for (int i = 0; i < NW; i++) { a += red[i]; b += red[NW + i]; }
        float mu = a * inv_n, ms = b * inv_n;
        *s_mu = mu;
        *s_rs = rsqrtf(ms - mu * mu + LN_EPS);
    }
    __syncthreads();
}

// conv KxK over M x M LDS map (stride M+1) -> ReLU into R, accumulating
// sum/sumsq. Weights [k][NPOS], lane-consecutive p -> coalesced reads.
template<int M, int K>
__device__ __forceinline__ void conv_lds(const float* __restrict__ I,
                                         const float* __restrict__ wT,
                                         const float* __restrict__ bias,
                                         float* __restrict__ R,
                                         float& lsum, float& lsq)
{
    constexpr int NPOS = M * M;
    constexpr int PADK = (K - 1) / 2;
    constexpr int STR = M + 1;
    constexpr int OPT = (NPOS + NT - 1) / NT;
    const int tid = threadIdx.x;

    #pragma unroll
    for (int o = 0; o < OPT; o++) {
        int p = tid + o * NT;
        if (NPOS < NT && p >= NPOS) break;
        int i = p / M, j = p % M;
        float acc = bias[p];
        #pragma unroll
        for (int ki = 0; ki < K; ki++) {
            int ii = i - PADK + ki;
            bool rok = (ii >= 0 && ii < M);
            #pragma unroll
            for (int kj = 0; kj < K; kj++) {
                int jj = j - PADK + kj;
                float iv = (rok && jj >= 0 && jj < M) ? I[ii * STR + jj] : 0.0f;
                acc += iv * wT[(ki * K + kj) * NPOS + p];
            }
        }
        float v = fmaxf(acc, 0.0f);
        R[i * STR + j] = v;
        lsum += v;
        lsq  += v * v;
    }
}

// LN (+ optional 2x2 maxpool) of raw map R (res N, stride N+1) -> I (res M).
template<int N, bool POOL>
__device__ __forceinline__ void transform(const float* __restrict__ R,
                                          float mu, float rs,
                                          const float* __restrict__ g,
                                          const float* __restrict__ b,
                                          float* __restrict__ I)
{
    constexpr int M = POOL ? N / 2 : N;
    constexpr int SR = N + 1, SI = M + 1;
    const int tid = threadIdx.x;
    for (int p = tid; p < M * M; p += NT) {
        int i = p / M, j = p % M;
        float v;
        if constexpr (POOL) {
            float best = -3.4e38f;
            #pragma unroll
            for (int dy = 0; dy < 2; dy++)
                #pragma unroll
                for (int dx = 0; dx < 2; dx++) {
                    int r = 2 * i + dy, c = 2 * j + dx;
                    float n = (R[r * SR + c] - mu) * rs * g[r * N + c] + b[r * N + c];
                    best = fmaxf(best, n);
                }
            v = best;
        } else {
            v = (R[i * SR + j] - mu) * rs * g[i * N + j] + b[i * N + j];
        }
        I[i * SI + j] = v;
    }
}

// ---------------------------------------------------------------------------
// K2: stages 2-6 + FC + softmax. One block (1024 thr) per sample.
// ---------------------------------------------------------------------------
__global__ __launch_bounds__(1024) void tail_fused(
    const float* __restrict__ ws_ro,
    const float* __restrict__ g1, const float* __restrict__ be1,
    const float* __restrict__ b2,
    const float* __restrict__ g2, const float* __restrict__ be2,
    const float* __restrict__ b3,
    const float* __restrict__ g3, const float* __restrict__ be3,
    const float* __restrict__ b4,
    const float* __restrict__ g4, const float* __restrict__ be4,
    const float* __restrict__ b5,
    const float* __restrict__ g5, const float* __restrict__ be5,
    const float* __restrict__ b6,
    const float* __restrict__ g6, const float* __restrict__ be6,
    const float* __restrict__ fcb,
    float* __restrict__ outp)
{
    __shared__ __align__(16) float I[64 * 65];
    __shared__ __align__(16) float R[64 * 65];
    __shared__ __align__(16) float h[256];
    __shared__ float red[2 * NW];
    __shared__ float s_mu, s_rs;

    const int s = blockIdx.x;
    const int tid = threadIdx.x;
    const float* x1  = ws_ro + T1_OFF + s * 16384;
    const float* wT2 = ws_ro + WT2_OFF;
    const float* wT3 = ws_ro + WT3_OFF;
    const float* wT4 = ws_ro + WT4_OFF;
    const float* wT5 = ws_ro + WT5_OFF;
    const float* wT6 = ws_ro + WT6_OFF;

    // LN1 stats over raw stage-1 output (float4)
    float ls = 0.f, lq = 0.f;
    {
        const float4* x4 = (const float4*)x1;
        #pragma unroll
        for (int i = tid; i < 4096; i += NT) {
            float4 v = x4[i];
            ls += v.x + v.y + v.z + v.w;
            lq += v.x * v.x + v.y * v.y + v.z * v.z + v.w * v.w;
        }
    }
    stats_reduce(red, ls, lq, 1.f / 16384.f, &s_mu, &s_rs);

    // pool(LN1(t1)) -> I (64x64, stride 65). float2 loads, lane-consecutive.
    {
        float mu = s_mu, rs = s_rs;
        #pragma unroll
        for (int o = 0; o < 4; o++) {
            int p = tid + o * NT;
            int i = p >> 6, j = p & 63;
            float2 xa = *((const float2*)(x1 + (2 * i) * 128 + 2 * j));
            float2 xb = *((const float2*)(x1 + (2 * i + 1) * 128 + 2 * j));
            float2 ga = *((const float2*)(g1 + (2 * i) * 128 + 2 * j));
            float2 gb = *((const float2*)(g1 + (2 * i + 1) * 128 + 2 * j));
            float2 ba = *((const float2*)(be1 + (2 * i) * 128 + 2 * j));
            float2 bb = *((const float2*)(be1 + (2 * i + 1) * 128 + 2 * j));
            float n0 = (xa.x - mu) * rs * ga.x + ba.x;
            float n1 = (xa.y - mu) * rs * ga.y + ba.y;
            float n2 = (xb.x - mu) * rs * gb.x + bb.x;
            float n3 = (xb.y - mu) * rs * gb.y + bb.y;
            I[i * 65 + j] = fmaxf(fmaxf(n0, n1), fmaxf(n2, n3));
        }
    }
    __syncthreads();

    float ls2, lq2;

    // S2: conv5 -> R, LN2
    ls2 = lq2 = 0.f; conv_lds<64, 5>(I, wT2, b2, R, ls2, lq2);
    stats_reduce(red, ls2, lq2, 1.f / 4096.f, &s_mu, &s_rs);
    transform<64, false>(R, s_mu, s_rs, g2, be2, I);
    __syncthreads();

    // S3: conv5 -> R, LN3, pool -> 32
    ls2 = lq2 = 0.f; conv_lds<64, 5>(I, wT3, b3, R, ls2, lq2);
    stats_reduce(red, ls2, lq2, 1.f / 4096.f, &s_mu, &s_rs);
    transform<64, true>(R, s_mu, s_rs, g3, be3, I);
    __syncthreads();

    // S4: conv3 (32) -> R, LN4
    ls2 = lq2 = 0.f; conv_lds<32, 3>(I, wT4, b4, R, ls2, lq2);
    stats_reduce(red, ls2, lq2, 1.f / 1024.f, &s_mu, &s_rs);
    transform<32, false>(R, s_mu, s_rs, g4, be4, I);
    __syncthreads();

    // S5: conv3 (32) -> R, LN5, pool -> 16
    ls2 = lq2 = 0.f; conv_lds<32, 3>(I, wT5, b5, R, ls2, lq2);
    stats_reduce(red, ls2, lq2, 1.f / 1024.f, &s_mu, &s_rs);
    transform<32, true>(R, s_mu, s_rs, g5, be5, I);
    __syncthreads();

    // S6: conv3 (16) -> R, LN6
    ls2 = lq2 = 0.f; conv_lds<16, 3>(I, wT6, b6, R, ls2, lq2);
    stats_reduce(red, ls2, lq2, 1.f / 256.f, &s_mu, &s_rs);

    // LN6 -> h[256]
    if (tid < 256) {
        int i = tid >> 4, j = tid & 15;
        h[tid] = (R[i * 17 + j] - s_mu) * s_rs * g6[tid] + be6[tid];
    }
    __syncthreads();

    // FC 256->1024: one logit/thread, 64 coalesced float4 weight loads.
    float acc = fcb[tid];
    {
        const float4* wq = (const float4*)(ws_ro + FCWT_OFF);
        const float4* h4 = (const float4*)h;
        #pragma unroll 8
        for (int kq = 0; kq < 64; kq++) {
            float4 wv = wq[kq * 1024 + tid];
            float4 hv = h4[kq];
            acc += wv.x * hv.x + wv.y * hv.y + wv.z * hv.z + wv.w * hv.w;
        }
    }

    // softmax over the block's 1024 logits
    float m = acc;
    #pragma unroll
    for (int off = 32; off > 0; off >>= 1)
        m = fmaxf(m, __shfl_down(m, off, 64));
    if ((tid & 63) == 0) red[tid >> 6] = m;
    __syncthreads();
    if (tid == 0) {
        float mm = red[0];
        #pragma unroll
        for (int i = 1; i < NW; i++) mm = fmaxf(mm, red[i]);
        s_mu = mm;
    }
    __syncthreads();
    float e = expf(acc - s_mu);
    float sum = e;
    #pragma unroll
    for (int off = 32; off > 0; off >>= 1)
        sum += __shfl_down(sum, off, 64);
    if ((tid & 63) == 0) red[NW + (tid >> 6)] = sum;
    __syncthreads();
    if (tid == 0) {
        float ss = 0.f;
        #pragma unroll
        for (int i = 0; i < NW; i++) ss += red[NW + i];
        s_rs = 1.0f / ss;
    }
    __syncthreads();
    outp[s * 1024 + tid] = e * s_rs;
}

// ---------------------------------------------------------------------------
extern "C" void kernel_launch(void* const* d_in, const int* in_sizes, int n_in,
                              void* d_out, int out_size, void* d_ws, size_t ws_size,
                              hipStream_t stream) {
    (void)in_sizes; (void)n_in; (void)out_size; (void)ws_size;

    const float* x   = (const float*)d_in[0];
    const float* w1  = (const float*)d_in[1];  const float* b1  = (const float*)d_in[2];
    const float* g1  = (const float*)d_in[3];  const float* be1 = (const float*)d_in[4];
    const float* w2  = (const float*)d_in[5];  const float* b2  = (const float*)d_in[6];
    const float* g2  = (const float*)d_in[7];  const float* be2 = (const float*)d_in[8];
    const float* w3  = (const float*)d_in[9];  const float* b3  = (const float*)d_in[10];
    const float* g3  = (const float*)d_in[11]; const float* be3 = (const float*)d_in[12];
    const float* w4  = (const float*)d_in[13]; const float* b4  = (const float*)d_in[14];
    const float* g4  = (const float*)d_in[15]; const float* be4 = (const float*)d_in[16];
    const float* w5  = (const float*)d_in[17]; const float* b5  = (const float*)d_in[18];
    const float* g5  = (const float*)d_in[19]; const float* be5 = (const float*)d_in[20];
    const float* w6  = (const float*)d_in[21]; const float* b6  = (const float*)d_in[22];
    const float* g6  = (const float*)d_in[23]; const float* be6 = (const float*)d_in[24];
    const float* fcw = (const float*)d_in[25]; const float* fcb = (const float*)d_in[26];

    float* ws = (float*)d_ws;

    s1_conv<<<NREP + 1024, 256, 0, stream>>>(x, w1, b1, w2, w3, w4, w5, w6, fcw, ws);
    tail_fused<<<64, 1024, 0, stream>>>((const float*)ws,
        g1, be1, b2, g2, be2, b3, g3, be3,
        b4, g4, be4, b5, g5, be5, b6, g6, be6,
        fcb, (float*)d_out);
}